// Round 1
// baseline (1758.498 us; speedup 1.0000x reference)
//
#include <hip/hip_runtime.h>
#include <math.h>

#define B_     8
#define C_     256
#define HW_    1024
#define NTOT   (B_*C_*HW_)     // 2097152
#define HEADS_ 8
#define DK_    32
#define SCALE_ 0.17677669529663687f  // 32^-0.5

// workspace layout (float offsets)
#define F_STATS 0
#define F_PART  16
#define F_YK    8192
#define F_YV    (F_YK + NTOT)
#define F_Q     (F_YV + NTOT)
#define F_K     (F_Q + NTOT)
#define F_V     (F_K + NTOT)
#define F_AO    F_YK            // alias: yk dead after projections

// ---------------- stage 1: global mean/var partials ----------------
__global__ void k_part(const float* __restrict__ x, float* __restrict__ part) {
    __shared__ float ls[4], ls2[4];
    float s = 0.f, s2 = 0.f;
    for (int i = blockIdx.x * 256 + threadIdx.x; i < NTOT; i += 2048 * 256) {
        float v = x[i]; s += v; s2 += v * v;
    }
    for (int o = 32; o; o >>= 1) { s += __shfl_down(s, o); s2 += __shfl_down(s2, o); }
    int wid = threadIdx.x >> 6, lane = threadIdx.x & 63;
    if (lane == 0) { ls[wid] = s; ls2[wid] = s2; }
    __syncthreads();
    if (threadIdx.x == 0) {
        float a = 0.f, b = 0.f;
        for (int i = 0; i < 4; i++) { a += ls[i]; b += ls2[i]; }
        part[blockIdx.x * 2] = a; part[blockIdx.x * 2 + 1] = b;
    }
}

__global__ void k_stats(const float* __restrict__ part, float* __restrict__ stats) {
    __shared__ float ls[256], ls2[256];
    float s = 0.f, s2 = 0.f;
    for (int i = threadIdx.x; i < 2048; i += 256) { s += part[2 * i]; s2 += part[2 * i + 1]; }
    ls[threadIdx.x] = s; ls2[threadIdx.x] = s2;
    __syncthreads();
    for (int off = 128; off; off >>= 1) {
        if (threadIdx.x < off) { ls[threadIdx.x] += ls[threadIdx.x + off]; ls2[threadIdx.x] += ls2[threadIdx.x + off]; }
        __syncthreads();
    }
    if (threadIdx.x == 0) {
        float m = ls[0] / (float)NTOT;
        float var = ls2[0] / (float)NTOT - m * m;
        stats[0] = m;
        stats[1] = rsqrtf(var + 1e-5f);
    }
}

// ---------------- stage 2: both 3x3 convs (k-path & v-path) ----------------
// grid: 2048 = b*256(co); block 256; each thread 4 pixels
__global__ void k_conv(const float* __restrict__ x,
                       const float* __restrict__ wk, const float* __restrict__ bk,
                       const float* __restrict__ wv, const float* __restrict__ bv,
                       float* __restrict__ yk, float* __restrict__ yv) {
    __shared__ float xs[4][HW_];
    int b = blockIdx.x >> 8, co = blockIdx.x & 255;
    int tid = threadIdx.x;
    float ak[4] = {0, 0, 0, 0}, av[4] = {0, 0, 0, 0};
    const float* xb = x + b * C_ * HW_;
    for (int c0 = 0; c0 < C_; c0 += 4) {
        for (int i = tid; i < 4 * HW_; i += 256)
            xs[i >> 10][i & 1023] = xb[c0 * HW_ + i];
        __syncthreads();
        for (int ci = 0; ci < 4; ci++) {
            const float* wkp = wk + (co * C_ + c0 + ci) * 9;
            const float* wvp = wv + (co * C_ + c0 + ci) * 9;
            float wk9[9], wv9[9];
            #pragma unroll
            for (int t = 0; t < 9; t++) { wk9[t] = wkp[t]; wv9[t] = wvp[t]; }
            #pragma unroll
            for (int k = 0; k < 4; k++) {
                int p = tid + k * 256;
                int yy = p >> 5, xx = p & 31;
                #pragma unroll
                for (int kh = 0; kh < 3; kh++) {
                    int y2 = yy + kh - 1;
                    if (y2 < 0 || y2 > 31) continue;
                    #pragma unroll
                    for (int kw = 0; kw < 3; kw++) {
                        int x2 = xx + kw - 1;
                        if (x2 < 0 || x2 > 31) continue;
                        float v = xs[ci][(y2 << 5) + x2];
                        ak[k] += v * wk9[kh * 3 + kw];
                        av[k] += v * wv9[kh * 3 + kw];
                    }
                }
            }
        }
        __syncthreads();
    }
    float bko = bk[co], bvo = bv[co];
    for (int k = 0; k < 4; k++) {
        int p = tid + k * 256;
        yk[(b * C_ + co) * HW_ + p] = ak[k] + bko;
        yv[(b * C_ + co) * HW_ + p] = av[k] + bvo;
    }
}

// ---------------- stage 3: q/k/v projections ----------------
// grid: 2048 = b*256 (i-tiles of 4); block 256 (one output channel each)
__global__ void k_proj(const float* __restrict__ x,
                       const float* __restrict__ yk, const float* __restrict__ yv,
                       const float* __restrict__ Wq, const float* __restrict__ bq,
                       const float* __restrict__ Wk, const float* __restrict__ bk,
                       const float* __restrict__ Wv, const float* __restrict__ bv,
                       const float* __restrict__ stats,
                       float* __restrict__ q, float* __restrict__ kk, float* __restrict__ vv) {
    __shared__ float xq[C_][4], xk[C_][4], xv[C_][4];
    int b = blockIdx.x >> 8, i0 = (blockIdx.x & 255) << 2;
    int e = threadIdx.x;
    float m = stats[0], r = stats[1];
    {
        float4 a = *(const float4*)&x[(b * C_ + e) * HW_ + i0];
        xq[e][0] = (a.x - m) * r; xq[e][1] = (a.y - m) * r;
        xq[e][2] = (a.z - m) * r; xq[e][3] = (a.w - m) * r;
        float4 kr = *(const float4*)&yk[(b * C_ + e) * HW_ + i0];
        xk[e][0] = kr.x; xk[e][1] = kr.y; xk[e][2] = kr.z; xk[e][3] = kr.w;
        float4 vr = *(const float4*)&yv[(b * C_ + e) * HW_ + i0];
        xv[e][0] = vr.x; xv[e][1] = vr.y; xv[e][2] = vr.z; xv[e][3] = vr.w;
    }
    __syncthreads();
    float aq[4], ak[4], av[4];
    float bqe = bq[e], bke = bk[e], bve = bv[e];
    #pragma unroll
    for (int ii = 0; ii < 4; ii++) { aq[ii] = bqe; ak[ii] = bke; av[ii] = bve; }
    for (int c = 0; c < C_; c++) {
        float wq_ = Wq[c * 256 + e], wk_ = Wk[c * 256 + e], wv_ = Wv[c * 256 + e];
        #pragma unroll
        for (int ii = 0; ii < 4; ii++) {
            aq[ii] += xq[c][ii] * wq_;
            ak[ii] += xk[c][ii] * wk_;
            av[ii] += xv[c][ii] * wv_;
        }
    }
    int h = e >> 5, d = e & 31;
    for (int ii = 0; ii < 4; ii++) {
        int oi = ((b * HEADS_ + h) * HW_ + i0 + ii) * DK_ + d;
        q[oi] = aq[ii]; kk[oi] = ak[ii]; vv[oi] = av[ii];
    }
}

// ---------------- stage 4: attention ----------------
// grid: 8192 = b*h*128 (i-tiles of 8); block 256
__global__ void k_attn(const float* __restrict__ q, const float* __restrict__ kk,
                       const float* __restrict__ vv, const float* __restrict__ Bb,
                       float* __restrict__ ao) {
    __shared__ float qs[8 * DK_];
    __shared__ float kt[128 * 33];
    __shared__ float p[8 * HW_];
    __shared__ float rsum[8];
    int bh = blockIdx.x >> 7;          // b*8+h
    int i0 = (blockIdx.x & 127) << 3;  // 8 query rows
    int b = bh >> 3, h = bh & 7;
    int tid = threadIdx.x;
    int r = tid >> 5, l = tid & 31;

    qs[tid] = q[(bh * HW_ + i0 + r) * DK_ + l];  // 256 = 8 rows x 32
    const float* kg = kk + bh * HW_ * DK_;
    const float* vg = vv + bh * HW_ * DK_;
    __syncthreads();

    // scores
    for (int jt = 0; jt < 8; jt++) {
        for (int t = tid; t < 128 * DK_; t += 256)
            kt[(t >> 5) * 33 + (t & 31)] = kg[jt * 4096 + t];
        __syncthreads();
        #pragma unroll
        for (int u = 0; u < 4; u++) {
            int jj = l + 32 * u;
            float acc = 0.f;
            #pragma unroll
            for (int d = 0; d < DK_; d++) acc += qs[r * DK_ + d] * kt[jj * 33 + d];
            int j = jt * 128 + jj;
            p[r * HW_ + j] = acc * SCALE_ + Bb[((h * HW_) + i0 + r) * HW_ + j];
        }
        __syncthreads();
    }

    // per-row softmax (32 lanes per row)
    float mx = -1e30f;
    for (int t = 0; t < 32; t++) mx = fmaxf(mx, p[r * HW_ + l + 32 * t]);
    for (int o = 16; o; o >>= 1) mx = fmaxf(mx, __shfl_xor(mx, o, 32));
    float ssum = 0.f;
    for (int t = 0; t < 32; t++) {
        float e_ = __expf(p[r * HW_ + l + 32 * t] - mx);
        p[r * HW_ + l + 32 * t] = e_;
        ssum += e_;
    }
    for (int o = 16; o; o >>= 1) ssum += __shfl_xor(ssum, o, 32);
    if (l == 0) rsum[r] = ssum;
    __syncthreads();

    // PV
    float acc = 0.f;
    for (int jt = 0; jt < 8; jt++) {
        for (int t = tid; t < 128 * DK_; t += 256)
            kt[(t >> 5) * 33 + (t & 31)] = vg[jt * 4096 + t];
        __syncthreads();
        for (int j = 0; j < 128; j++)
            acc += p[r * HW_ + jt * 128 + j] * kt[j * 33 + l];
        __syncthreads();
    }
    float outv = acc / rsum[r];
    ao[(b * HW_ + i0 + r) * C_ + h * DK_ + l] = outv;
}

// ---------------- stage 5: output projection + raw-reshape residual ----------------
// grid: 2048 = b*256 (i-tiles of 4); block 256
__global__ void k_out(const float* __restrict__ ao, const float* __restrict__ Wo,
                      const float* __restrict__ bo, const float* __restrict__ x,
                      float* __restrict__ out) {
    __shared__ float as_[C_][4];
    int b = blockIdx.x >> 8, i0 = (blockIdx.x & 255) << 2;
    int e = threadIdx.x;
    for (int ii = 0; ii < 4; ii++)
        as_[e][ii] = ao[(b * HW_ + i0 + ii) * C_ + e];
    __syncthreads();
    float acc[4];
    float boe = bo[e];
    #pragma unroll
    for (int ii = 0; ii < 4; ii++) acc[ii] = boe;
    for (int c = 0; c < C_; c++) {
        float w = Wo[c * 256 + e];
        #pragma unroll
        for (int ii = 0; ii < 4; ii++) acc[ii] += as_[c][ii] * w;
    }
    for (int ii = 0; ii < 4; ii++) {
        int idx = b * (C_ * HW_) + (i0 + ii) * 256 + e;  // raw reshape: same flat index
        out[idx] = acc[ii] + x[idx];
    }
}

extern "C" void kernel_launch(void* const* d_in, const int* in_sizes, int n_in,
                              void* d_out, int out_size, void* d_ws, size_t ws_size,
                              hipStream_t stream) {
    const float* x   = (const float*)d_in[0];
    const float* Wq  = (const float*)d_in[1];
    const float* bq  = (const float*)d_in[2];
    const float* ckw = (const float*)d_in[3];
    const float* ckb = (const float*)d_in[4];
    const float* Wk  = (const float*)d_in[5];
    const float* bk  = (const float*)d_in[6];
    const float* cvw = (const float*)d_in[7];
    const float* cvb = (const float*)d_in[8];
    const float* Wv  = (const float*)d_in[9];
    const float* bv  = (const float*)d_in[10];
    const float* Wo  = (const float*)d_in[11];
    const float* bo  = (const float*)d_in[12];
    const float* Bb  = (const float*)d_in[13];
    float* ws  = (float*)d_ws;
    float* out = (float*)d_out;

    k_part <<<2048, 256, 0, stream>>>(x, ws + F_PART);
    k_stats<<<1,    256, 0, stream>>>(ws + F_PART, ws + F_STATS);
    k_conv <<<2048, 256, 0, stream>>>(x, ckw, ckb, cvw, cvb, ws + F_YK, ws + F_YV);
    k_proj <<<2048, 256, 0, stream>>>(x, ws + F_YK, ws + F_YV,
                                      Wq, bq, Wk, bk, Wv, bv,
                                      ws + F_STATS, ws + F_Q, ws + F_K, ws + F_V);
    k_attn <<<8192, 256, 0, stream>>>(ws + F_Q, ws + F_K, ws + F_V, Bb, ws + F_AO);
    k_out  <<<2048, 256, 0, stream>>>(ws + F_AO, Wo, bo, x, out);
}

// Round 3
// 976.732 us; speedup vs baseline: 1.8004x; 1.8004x over previous
//
#include <hip/hip_runtime.h>
#include <hip/hip_bf16.h>
#include <math.h>

#define B_     8
#define C_     256
#define HW_    1024
#define NTOT   (B_*C_*HW_)     // 2097152
#define HEADS_ 8
#define DK_    32
#define SCALE_ 0.17677669529663687f  // 32^-0.5

// workspace layout (float offsets)
#define F_STATS 0
#define F_PART  16
#define F_Q     8192
#define F_K     (F_Q + NTOT)
#define F_V     (F_K + NTOT)
#define F_YK2   (F_V + NTOT)
#define F_YV2   (F_YK2 + NTOT)
#define F_AO    F_YK2           // alias: yk2 dead after projections

typedef float f32x4 __attribute__((ext_vector_type(4)));
typedef short short8 __attribute__((ext_vector_type(8)));

// ---------------- stage 1: global mean/var partials ----------------
__global__ void k_part(const float* __restrict__ x, float* __restrict__ part) {
    __shared__ float ls[4], ls2[4];
    float s = 0.f, s2 = 0.f;
    for (int i = blockIdx.x * 256 + threadIdx.x; i < NTOT; i += 2048 * 256) {
        float v = x[i]; s += v; s2 += v * v;
    }
    for (int o = 32; o; o >>= 1) { s += __shfl_down(s, o); s2 += __shfl_down(s2, o); }
    int wid = threadIdx.x >> 6, lane = threadIdx.x & 63;
    if (lane == 0) { ls[wid] = s; ls2[wid] = s2; }
    __syncthreads();
    if (threadIdx.x == 0) {
        float a = 0.f, b = 0.f;
        for (int i = 0; i < 4; i++) { a += ls[i]; b += ls2[i]; }
        part[blockIdx.x * 2] = a; part[blockIdx.x * 2 + 1] = b;
    }
}

__global__ void k_stats(const float* __restrict__ part, float* __restrict__ stats) {
    __shared__ float ls[256], ls2[256];
    float s = 0.f, s2 = 0.f;
    for (int i = threadIdx.x; i < 2048; i += 256) { s += part[2 * i]; s2 += part[2 * i + 1]; }
    ls[threadIdx.x] = s; ls2[threadIdx.x] = s2;
    __syncthreads();
    for (int off = 128; off; off >>= 1) {
        if (threadIdx.x < off) { ls[threadIdx.x] += ls[threadIdx.x + off]; ls2[threadIdx.x] += ls2[threadIdx.x + off]; }
        __syncthreads();
    }
    if (threadIdx.x == 0) {
        float m = ls[0] / (float)NTOT;
        float var = ls2[0] / (float)NTOT - m * m;
        stats[0] = m;
        stats[1] = rsqrtf(var + 1e-5f);
    }
}

// ---------------- prep: x -> xb[b][p][ci] bf16 (transposed, ci-contiguous) ----
// grid 128 = 8 b x 16 ptiles(64 p); block 256
__global__ void k_prep_x(const float* __restrict__ x, short* __restrict__ xb) {
    __shared__ short t[64 * 258];   // stride 258 shorts = 129 words -> conflict-free
    int b = blockIdx.x >> 4, p0 = (blockIdx.x & 15) << 6;
    int tid = threadIdx.x;
    for (int i = tid; i < 256 * 64; i += 256) {
        int ci = i >> 6, p = i & 63;
        float v = x[(b * C_ + ci) * HW_ + p0 + p];
        __hip_bfloat16 h = __float2bfloat16(v);
        t[p * 258 + ci] = *(short*)&h;
    }
    __syncthreads();
    for (int i = tid; i < 64 * 256; i += 256) {
        int p = i >> 8, ci = i & 255;
        xb[(b * HW_ + p0 + p) * C_ + ci] = t[p * 258 + ci];
    }
}

// ---------------- prep: weights -> Wt2[tap][n(512)][ci] bf16 ----------------
// n<256: conv_k co=n ; n>=256: conv_v co=n-256
__global__ void k_prep_w(const float* __restrict__ wk, const float* __restrict__ wv,
                         short* __restrict__ wt) {
    int idx = blockIdx.x * 256 + threadIdx.x;      // 294912 threads, 4 elems each
    int ci0 = (idx << 2) & 255;
    int rest = idx >> 6;
    int n = rest & 511, tap = rest >> 9;
    const float* src = (n < 256) ? (wk + (n * C_) * 9) : (wv + ((n - 256) * C_) * 9);
    short4 o;
    short* op = (short*)&o;
    for (int u = 0; u < 4; u++) {
        float v = src[(ci0 + u) * 9 + tap];
        __hip_bfloat16 h = __float2bfloat16(v);
        op[u] = *(short*)&h;
    }
    *(short4*)&wt[((tap * 512 + n) * C_) + ci0] = o;
}

// ---------------- conv via MFMA implicit GEMM (both convs, N=512) -----------
// grid 512 = b(8) x ptile(16, 2 image rows = 64 px) x ntile(4, 128 cols)
// block 256 = 4 waves (wm = w>>1 row-half, wn = w&1 col-half): wave = 32px x 64co
__device__ __forceinline__ int a_off(int slot, int chunk) {
    int c = chunk ^ (slot & 3);
    int s = slot ^ ((slot >> 2) & 1);
    return s * 64 + c * 16;   // byte offset
}

__global__ void k_conv_mfma(const short* __restrict__ xb, const short* __restrict__ wt,
                            const float* __restrict__ bk, const float* __restrict__ bv,
                            float* __restrict__ yk2, float* __restrict__ yv2) {
    __shared__ short a_lds[136 * 32];   // [4 rows][34 cols][32 ci], swizzled; 8704 B
    int bid = blockIdx.x;
    int b = bid >> 6, pt = (bid >> 2) & 15, nt = bid & 3;
    int R0 = pt * 2;                    // image rows R0..R0+1
    int tid = threadIdx.x;
    int w = tid >> 6, l = tid & 63;
    int wm = w >> 1, wn = w & 1;
    int col16 = l & 15, kq = l >> 4;

    f32x4 acc[2][4];
    #pragma unroll
    for (int m = 0; m < 2; m++)
        #pragma unroll
        for (int n = 0; n < 4; n++) acc[m][n] = (f32x4)0.f;

    const short* wbase = wt + (nt * 128 + wn * 64 + col16) * C_ + kq * 8;

    for (int ci0 = 0; ci0 < C_; ci0 += 32) {
        if (ci0) __syncthreads();
        // stage A tile: 4 rows x 34 cols x 32 ci
        for (int i = tid; i < 544; i += 256) {
            int slot = i >> 2, chunk = i & 3;
            int ty = slot / 34, tx = slot - ty * 34;
            int Y = R0 - 1 + ty, X = tx - 1;
            short8 v = (short8)0;
            if ((unsigned)Y < 32u && (unsigned)X < 32u)
                v = *(const short8*)(xb + ((b * HW_ + Y * 32 + X) * C_ + ci0 + chunk * 8));
            *(short8*)((char*)a_lds + a_off(slot, chunk)) = v;
        }
        __syncthreads();

        #pragma unroll
        for (int tap = 0; tap < 9; tap++) {
            const int dyi = tap / 3, dxi = tap % 3;
            short8 bf[4];
            #pragma unroll
            for (int nf = 0; nf < 4; nf++)
                bf[nf] = *(const short8*)(wbase + (tap * 512 + nf * 16) * C_ + ci0);
            short8 af[2];
            #pragma unroll
            for (int mf = 0; mf < 2; mf++) {
                int r = wm * 32 + mf * 16 + col16;
                int slot = ((r >> 5) + dyi) * 34 + (r & 31) + dxi;
                af[mf] = *(const short8*)((char*)a_lds + a_off(slot, kq));
            }
            #pragma unroll
            for (int mf = 0; mf < 2; mf++)
                #pragma unroll
                for (int nf = 0; nf < 4; nf++)
                    acc[mf][nf] = __builtin_amdgcn_mfma_f32_16x16x32_bf16(af[mf], bf[nf], acc[mf][nf], 0, 0, 0);
        }
    }

    // epilogue: bias + store to y[b][p][co] (k-conv: nt<2, v-conv: nt>=2)
    const bool isv = (nt >= 2);
    float* dst = isv ? yv2 : yk2;
    const float* bias = isv ? bv : bk;
    int cbase = ((nt & 1) * 128) + wn * 64 + col16;
    #pragma unroll
    for (int nf = 0; nf < 4; nf++) {
        int co = cbase + nf * 16;
        float bi = bias[co];
        #pragma unroll
        for (int mf = 0; mf < 2; mf++) {
            #pragma unroll
            for (int r = 0; r < 4; r++) {
                int pixel = pt * 64 + wm * 32 + mf * 16 + kq * 4 + r;
                dst[(b * HW_ + pixel) * C_ + co] = acc[mf][nf][r] + bi;
            }
        }
    }
}

// ---------------- stage 3: q/k/v projections ----------------
// grid: 2048 = b*256 (i-tiles of 4); block 256 (one output channel each)
__global__ void k_proj(const float* __restrict__ x,
                       const float* __restrict__ yk2, const float* __restrict__ yv2,
                       const float* __restrict__ Wq, const float* __restrict__ bq,
                       const float* __restrict__ Wk, const float* __restrict__ bk,
                       const float* __restrict__ Wv, const float* __restrict__ bv,
                       const float* __restrict__ stats,
                       float* __restrict__ q, float* __restrict__ kk, float* __restrict__ vv) {
    __shared__ float xq[C_][4], xk[C_][4], xv[C_][4];
    int b = blockIdx.x >> 8, i0 = (blockIdx.x & 255) << 2;
    int e = threadIdx.x;
    float m = stats[0], r = stats[1];
    {
        float4 a = *(const float4*)&x[(b * C_ + e) * HW_ + i0];
        xq[e][0] = (a.x - m) * r; xq[e][1] = (a.y - m) * r;
        xq[e][2] = (a.z - m) * r; xq[e][3] = (a.w - m) * r;
        #pragma unroll
        for (int ii = 0; ii < 4; ii++) {
            xk[e][ii] = yk2[(b * HW_ + i0 + ii) * C_ + e];
            xv[e][ii] = yv2[(b * HW_ + i0 + ii) * C_ + e];
        }
    }
    __syncthreads();
    float aq[4], ak[4], av[4];
    float bqe = bq[e], bke = bk[e], bve = bv[e];
    #pragma unroll
    for (int ii = 0; ii < 4; ii++) { aq[ii] = bqe; ak[ii] = bke; av[ii] = bve; }
    for (int c = 0; c < C_; c++) {
        float wq_ = Wq[c * 256 + e], wk_ = Wk[c * 256 + e], wv_ = Wv[c * 256 + e];
        #pragma unroll
        for (int ii = 0; ii < 4; ii++) {
            aq[ii] += xq[c][ii] * wq_;
            ak[ii] += xk[c][ii] * wk_;
            av[ii] += xv[c][ii] * wv_;
        }
    }
    int h = e >> 5, d = e & 31;
    for (int ii = 0; ii < 4; ii++) {
        int oi = ((b * HEADS_ + h) * HW_ + i0 + ii) * DK_ + d;
        q[oi] = aq[ii]; kk[oi] = ak[ii]; vv[oi] = av[ii];
    }
}

// ---------------- stage 4: attention ----------------
// grid: 8192 = b*h*128 (i-tiles of 8); block 256
__global__ void k_attn(const float* __restrict__ q, const float* __restrict__ kk,
                       const float* __restrict__ vv, const float* __restrict__ Bb,
                       float* __restrict__ ao) {
    __shared__ float qs[8 * DK_];
    __shared__ float kt[128 * 33];
    __shared__ float p[8 * HW_];
    __shared__ float rsum[8];
    int bh = blockIdx.x >> 7;          // b*8+h
    int i0 = (blockIdx.x & 127) << 3;  // 8 query rows
    int b = bh >> 3, h = bh & 7;
    int tid = threadIdx.x;
    int r = tid >> 5, l = tid & 31;

    qs[tid] = q[(bh * HW_ + i0 + r) * DK_ + l];  // 256 = 8 rows x 32
    const float* kg = kk + bh * HW_ * DK_;
    const float* vg = vv + bh * HW_ * DK_;
    __syncthreads();

    // scores
    for (int jt = 0; jt < 8; jt++) {
        for (int t = tid; t < 128 * DK_; t += 256)
            kt[(t >> 5) * 33 + (t & 31)] = kg[jt * 4096 + t];
        __syncthreads();
        #pragma unroll
        for (int u = 0; u < 4; u++) {
            int jj = l + 32 * u;
            float acc = 0.f;
            #pragma unroll
            for (int d = 0; d < DK_; d++) acc += qs[r * DK_ + d] * kt[jj * 33 + d];
            int j = jt * 128 + jj;
            p[r * HW_ + j] = acc * SCALE_ + Bb[((h * HW_) + i0 + r) * HW_ + j];
        }
        __syncthreads();
    }

    // per-row softmax (32 lanes per row)
    float mx = -1e30f;
    for (int t = 0; t < 32; t++) mx = fmaxf(mx, p[r * HW_ + l + 32 * t]);
    for (int o = 16; o; o >>= 1) mx = fmaxf(mx, __shfl_xor(mx, o, 32));
    float ssum = 0.f;
    for (int t = 0; t < 32; t++) {
        float e_ = __expf(p[r * HW_ + l + 32 * t] - mx);
        p[r * HW_ + l + 32 * t] = e_;
        ssum += e_;
    }
    for (int o = 16; o; o >>= 1) ssum += __shfl_xor(ssum, o, 32);
    if (l == 0) rsum[r] = ssum;
    __syncthreads();

    // PV
    float acc = 0.f;
    for (int jt = 0; jt < 8; jt++) {
        for (int t = tid; t < 128 * DK_; t += 256)
            kt[(t >> 5) * 33 + (t & 31)] = vg[jt * 4096 + t];
        __syncthreads();
        for (int j = 0; j < 128; j++)
            acc += p[r * HW_ + jt * 128 + j] * kt[j * 33 + l];
        __syncthreads();
    }
    float outv = acc / rsum[r];
    ao[(b * HW_ + i0 + r) * C_ + h * DK_ + l] = outv;
}

// ---------------- stage 5: output projection + raw-reshape residual ----------
// grid: 2048 = b*256 (i-tiles of 4); block 256
__global__ void k_out(const float* __restrict__ ao, const float* __restrict__ Wo,
                      const float* __restrict__ bo, const float* __restrict__ x,
                      float* __restrict__ out) {
    __shared__ float as_[C_][4];
    int b = blockIdx.x >> 8, i0 = (blockIdx.x & 255) << 2;
    int e = threadIdx.x;
    for (int ii = 0; ii < 4; ii++)
        as_[e][ii] = ao[(b * HW_ + i0 + ii) * C_ + e];
    __syncthreads();
    float acc[4];
    float boe = bo[e];
    #pragma unroll
    for (int ii = 0; ii < 4; ii++) acc[ii] = boe;
    for (int c = 0; c < C_; c++) {
        float w = Wo[c * 256 + e];
        #pragma unroll
        for (int ii = 0; ii < 4; ii++) acc[ii] += as_[c][ii] * w;
    }
    for (int ii = 0; ii < 4; ii++) {
        int idx = b * (C_ * HW_) + (i0 + ii) * 256 + e;  // raw reshape: same flat index
        out[idx] = acc[ii] + x[idx];
    }
}

extern "C" void kernel_launch(void* const* d_in, const int* in_sizes, int n_in,
                              void* d_out, int out_size, void* d_ws, size_t ws_size,
                              hipStream_t stream) {
    const float* x   = (const float*)d_in[0];
    const float* Wq  = (const float*)d_in[1];
    const float* bq  = (const float*)d_in[2];
    const float* ckw = (const float*)d_in[3];
    const float* ckb = (const float*)d_in[4];
    const float* Wk  = (const float*)d_in[5];
    const float* bk  = (const float*)d_in[6];
    const float* cvw = (const float*)d_in[7];
    const float* cvb = (const float*)d_in[8];
    const float* Wv  = (const float*)d_in[9];
    const float* bv  = (const float*)d_in[10];
    const float* Wo  = (const float*)d_in[11];
    const float* bo  = (const float*)d_in[12];
    const float* Bb  = (const float*)d_in[13];
    float* ws  = (float*)d_ws;
    float* out = (float*)d_out;

    short* xb = (short*)(ws + F_Q);   // 2M bf16, dead after conv (q overwrites)
    short* wt = (short*)(ws + F_K);   // 1.18M bf16, dead after conv (k overwrites)

    k_part    <<<2048, 256, 0, stream>>>(x, ws + F_PART);
    k_stats   <<<1,    256, 0, stream>>>(ws + F_PART, ws + F_STATS);
    k_prep_x  <<<128,  256, 0, stream>>>(x, xb);
    k_prep_w  <<<1152, 256, 0, stream>>>(ckw, cvw, wt);
    k_conv_mfma<<<512, 256, 0, stream>>>(xb, wt, ckb, cvb, ws + F_YK2, ws + F_YV2);
    k_proj    <<<2048, 256, 0, stream>>>(x, ws + F_YK2, ws + F_YV2,
                                         Wq, bq, Wk, bk, Wv, bv,
                                         ws + F_STATS, ws + F_Q, ws + F_K, ws + F_V);
    k_attn    <<<8192, 256, 0, stream>>>(ws + F_Q, ws + F_K, ws + F_V, Bb, ws + F_AO);
    k_out     <<<2048, 256, 0, stream>>>(ws + F_AO, Wo, bo, x, out);
}

// Round 5
// 241.144 us; speedup vs baseline: 7.2923x; 4.0504x over previous
//
#include <hip/hip_runtime.h>
#include <hip/hip_bf16.h>
#include <math.h>

#define B_     8
#define C_     256
#define HW_    1024
#define NTOT   (B_*C_*HW_)     // 2097152
#define HEADS_ 8
#define DK_    32
#define SCALE_ 0.17677669529663687f  // 32^-0.5

// workspace layout (float offsets)
#define F_STATS 0
#define F_PART  16
#define F_YK2   8192
#define F_YV2   (F_YK2 + NTOT)
#define F_XB    (F_YV2 + NTOT)            // NTOT shorts = NTOT/2 floats
#define F_WT    (F_XB + NTOT/2)           // 1179648 shorts = 589824 floats
#define F_QB    (F_WT + 589824)           // NTOT/2 floats (bf16 q, scale folded)
#define F_KB    (F_QB + NTOT/2)
#define F_VT    (F_KB + NTOT/2)
#define F_AO    F_YK2                     // alias: yk2 dead after projections

typedef float f32x4 __attribute__((ext_vector_type(4)));
typedef short short8 __attribute__((ext_vector_type(8)));
typedef unsigned uint32x2 __attribute__((ext_vector_type(2)));

__device__ __forceinline__ unsigned pack_bf16(float a, float b) {
    __hip_bfloat16 ha = __float2bfloat16(a);
    __hip_bfloat16 hb = __float2bfloat16(b);
    unsigned ua = *(unsigned short*)&ha;
    unsigned ub = *(unsigned short*)&hb;
    return ua | (ub << 16);
}

// ---------------- stage 1: global mean/var partials ----------------
__global__ void k_part(const float* __restrict__ x, float* __restrict__ part) {
    __shared__ float ls[4], ls2[4];
    float s = 0.f, s2 = 0.f;
    for (int i = blockIdx.x * 256 + threadIdx.x; i < NTOT; i += 2048 * 256) {
        float v = x[i]; s += v; s2 += v * v;
    }
    for (int o = 32; o; o >>= 1) { s += __shfl_down(s, o); s2 += __shfl_down(s2, o); }
    int wid = threadIdx.x >> 6, lane = threadIdx.x & 63;
    if (lane == 0) { ls[wid] = s; ls2[wid] = s2; }
    __syncthreads();
    if (threadIdx.x == 0) {
        float a = 0.f, b = 0.f;
        for (int i = 0; i < 4; i++) { a += ls[i]; b += ls2[i]; }
        part[blockIdx.x * 2] = a; part[blockIdx.x * 2 + 1] = b;
    }
}

__global__ void k_stats(const float* __restrict__ part, float* __restrict__ stats) {
    __shared__ float ls[256], ls2[256];
    float s = 0.f, s2 = 0.f;
    for (int i = threadIdx.x; i < 2048; i += 256) { s += part[2 * i]; s2 += part[2 * i + 1]; }
    ls[threadIdx.x] = s; ls2[threadIdx.x] = s2;
    __syncthreads();
    for (int off = 128; off; off >>= 1) {
        if (threadIdx.x < off) { ls[threadIdx.x] += ls[threadIdx.x + off]; ls2[threadIdx.x] += ls2[threadIdx.x + off]; }
        __syncthreads();
    }
    if (threadIdx.x == 0) {
        float m = ls[0] / (float)NTOT;
        float var = ls2[0] / (float)NTOT - m * m;
        stats[0] = m;
        stats[1] = rsqrtf(var + 1e-5f);
    }
}

// ---------------- prep: x -> xb[b][p][ci] bf16 (transposed, ci-contiguous) ----
__global__ void k_prep_x(const float* __restrict__ x, short* __restrict__ xb) {
    __shared__ short t[64 * 258];
    int b = blockIdx.x >> 4, p0 = (blockIdx.x & 15) << 6;
    int tid = threadIdx.x;
    for (int i = tid; i < 256 * 64; i += 256) {
        int ci = i >> 6, p = i & 63;
        float v = x[(b * C_ + ci) * HW_ + p0 + p];
        __hip_bfloat16 h = __float2bfloat16(v);
        t[p * 258 + ci] = *(short*)&h;
    }
    __syncthreads();
    for (int i = tid; i < 64 * 256; i += 256) {
        int p = i >> 8, ci = i & 255;
        xb[(b * HW_ + p0 + p) * C_ + ci] = t[p * 258 + ci];
    }
}

// ---------------- prep: weights -> Wt2[tap][n(512)][ci] bf16 ----------------
__global__ void k_prep_w(const float* __restrict__ wk, const float* __restrict__ wv,
                         short* __restrict__ wt) {
    int idx = blockIdx.x * 256 + threadIdx.x;
    int ci0 = (idx << 2) & 255;
    int rest = idx >> 6;
    int n = rest & 511, tap = rest >> 9;
    const float* src = (n < 256) ? (wk + (n * C_) * 9) : (wv + ((n - 256) * C_) * 9);
    short4 o;
    short* op = (short*)&o;
    for (int u = 0; u < 4; u++) {
        float v = src[(ci0 + u) * 9 + tap];
        __hip_bfloat16 h = __float2bfloat16(v);
        op[u] = *(short*)&h;
    }
    *(short4*)&wt[((tap * 512 + n) * C_) + ci0] = o;
}

// ---------------- conv via MFMA implicit GEMM (both convs, N=512) -----------
__device__ __forceinline__ int a_off(int slot, int chunk) {
    int c = chunk ^ (slot & 3);
    int s = slot ^ ((slot >> 2) & 1);
    return s * 64 + c * 16;
}

__global__ void k_conv_mfma(const short* __restrict__ xb, const short* __restrict__ wt,
                            const float* __restrict__ bk, const float* __restrict__ bv,
                            float* __restrict__ yk2, float* __restrict__ yv2) {
    __shared__ short a_lds[136 * 32];
    int bid = blockIdx.x;
    int b = bid >> 6, pt = (bid >> 2) & 15, nt = bid & 3;
    int R0 = pt * 2;
    int tid = threadIdx.x;
    int w = tid >> 6, l = tid & 63;
    int wm = w >> 1, wn = w & 1;
    int col16 = l & 15, kq = l >> 4;

    f32x4 acc[2][4];
    #pragma unroll
    for (int m = 0; m < 2; m++)
        #pragma unroll
        for (int n = 0; n < 4; n++) acc[m][n] = (f32x4)0.f;

    const short* wbase = wt + (nt * 128 + wn * 64 + col16) * C_ + kq * 8;

    for (int ci0 = 0; ci0 < C_; ci0 += 32) {
        if (ci0) __syncthreads();
        for (int i = tid; i < 544; i += 256) {
            int slot = i >> 2, chunk = i & 3;
            int ty = slot / 34, tx = slot - ty * 34;
            int Y = R0 - 1 + ty, X = tx - 1;
            short8 v = (short8)0;
            if ((unsigned)Y < 32u && (unsigned)X < 32u)
                v = *(const short8*)(xb + ((b * HW_ + Y * 32 + X) * C_ + ci0 + chunk * 8));
            *(short8*)((char*)a_lds + a_off(slot, chunk)) = v;
        }
        __syncthreads();

        #pragma unroll
        for (int tap = 0; tap < 9; tap++) {
            const int dyi = tap / 3, dxi = tap % 3;
            short8 bf[4];
            #pragma unroll
            for (int nf = 0; nf < 4; nf++)
                bf[nf] = *(const short8*)(wbase + (tap * 512 + nf * 16) * C_ + ci0);
            short8 af[2];
            #pragma unroll
            for (int mf = 0; mf < 2; mf++) {
                int r = wm * 32 + mf * 16 + col16;
                int slot = ((r >> 5) + dyi) * 34 + (r & 31) + dxi;
                af[mf] = *(const short8*)((char*)a_lds + a_off(slot, kq));
            }
            #pragma unroll
            for (int mf = 0; mf < 2; mf++)
                #pragma unroll
                for (int nf = 0; nf < 4; nf++)
                    acc[mf][nf] = __builtin_amdgcn_mfma_f32_16x16x32_bf16(af[mf], bf[nf], acc[mf][nf], 0, 0, 0);
        }
    }

    const bool isv = (nt >= 2);
    float* dst = isv ? yv2 : yk2;
    const float* bias = isv ? bv : bk;
    int cbase = ((nt & 1) * 128) + wn * 64 + col16;
    #pragma unroll
    for (int nf = 0; nf < 4; nf++) {
        int co = cbase + nf * 16;
        float bi = bias[co];
        #pragma unroll
        for (int mf = 0; mf < 2; mf++) {
            #pragma unroll
            for (int r = 0; r < 4; r++) {
                int pixel = pt * 64 + wm * 32 + mf * 16 + kq * 4 + r;
                dst[(b * HW_ + pixel) * C_ + co] = acc[mf][nf][r] + bi;
            }
        }
    }
}

// ---------------- stage 3: q/k/v projections -> bf16 qb/kb/vt ---------------
__global__ void k_proj(const float* __restrict__ x,
                       const float* __restrict__ yk2, const float* __restrict__ yv2,
                       const float* __restrict__ Wq, const float* __restrict__ bq,
                       const float* __restrict__ Wk, const float* __restrict__ bk,
                       const float* __restrict__ Wv, const float* __restrict__ bv,
                       const float* __restrict__ stats,
                       short* __restrict__ qb, short* __restrict__ kb, short* __restrict__ vt) {
    __shared__ float xq[C_][4], xk[C_][4], xv[C_][4];
    int b = blockIdx.x >> 8, i0 = (blockIdx.x & 255) << 2;
    int e = threadIdx.x;
    float m = stats[0], r = stats[1];
    {
        float4 a = *(const float4*)&x[(b * C_ + e) * HW_ + i0];
        xq[e][0] = (a.x - m) * r; xq[e][1] = (a.y - m) * r;
        xq[e][2] = (a.z - m) * r; xq[e][3] = (a.w - m) * r;
        #pragma unroll
        for (int ii = 0; ii < 4; ii++) {
            xk[e][ii] = yk2[(b * HW_ + i0 + ii) * C_ + e];
            xv[e][ii] = yv2[(b * HW_ + i0 + ii) * C_ + e];
        }
    }
    __syncthreads();
    float aq[4], ak[4], av[4];
    float bqe = bq[e], bke = bk[e], bve = bv[e];
    #pragma unroll
    for (int ii = 0; ii < 4; ii++) { aq[ii] = bqe; ak[ii] = bke; av[ii] = bve; }
    for (int c = 0; c < C_; c++) {
        float wq_ = Wq[c * 256 + e], wk_ = Wk[c * 256 + e], wv_ = Wv[c * 256 + e];
        #pragma unroll
        for (int ii = 0; ii < 4; ii++) {
            aq[ii] += xq[c][ii] * wq_;
            ak[ii] += xk[c][ii] * wk_;
            av[ii] += xv[c][ii] * wv_;
        }
    }
    int h = e >> 5, d = e & 31;
    int bh = b * HEADS_ + h;
    short4 vv4;
    short* vp = (short*)&vv4;
    #pragma unroll
    for (int ii = 0; ii < 4; ii++) {
        __hip_bfloat16 hq = __float2bfloat16(aq[ii] * SCALE_);
        __hip_bfloat16 hk = __float2bfloat16(ak[ii]);
        __hip_bfloat16 hv = __float2bfloat16(av[ii]);
        qb[(bh * HW_ + i0 + ii) * DK_ + d] = *(short*)&hq;
        kb[(bh * HW_ + i0 + ii) * DK_ + d] = *(short*)&hk;
        vp[ii] = *(short*)&hv;
    }
    *(short4*)&vt[(bh * DK_ + d) * HW_ + i0] = vv4;   // V transposed: [bh][dv][p]
}

// ---------------- stage 4: attention (MFMA flash, swapped QK^T) -------------
// grid: 1024 = qt(16) x b(8) x h(8), h in low bits for XCD-L2 B locality
// block 256 = 4 waves; wave w owns queries qt*64 + w*16 .. +15
__global__ void k_attn(const short* __restrict__ qb, const short* __restrict__ kb,
                       const short* __restrict__ vt, const float* __restrict__ Bb,
                       float* __restrict__ ao) {
    __shared__ __align__(16) short Qs[64 * 32];      // [q][d] linear
    __shared__ __align__(16) short Ks[64 * 32];      // [key][d] linear
    __shared__ __align__(16) short Vs[32 * 64];      // [dv][key], XOR-swizzled
    __shared__ __align__(16) short Ps[4][16 * 64];   // per-wave P, XOR-swizzled
    int bid = blockIdx.x;
    int h = bid & 7, b = (bid >> 3) & 7, qt = bid >> 6;
    int bh = b * HEADS_ + h;
    int tid = threadIdx.x, w = tid >> 6, l = tid & 63;
    int g = l >> 4, c16 = l & 15;

    // Q tile (64 q x 32 d), linear: 256 threads x 8 shorts
    *(short8*)(Qs + tid * 8) = *(const short8*)(qb + (bh * HW_ + qt * 64) * DK_ + tid * 8);

    const float* Brow = Bb + (h * HW_ + qt * 64 + w * 16 + c16) * HW_;  // this lane's q row
    float m_run = -1e30f, l_run = 0.f;
    f32x4 ot[2];
    ot[0] = (f32x4)0.f; ot[1] = (f32x4)0.f;
    char* pbase = (char*)&Ps[w][0];
    int vrow = tid >> 3, vch = tid & 7;

    for (int kv0 = 0; kv0 < HW_; kv0 += 64) {
        __syncthreads();   // prior compute done (also covers initial Q write)
        // stage K tile [64][32] linear
        *(short8*)(Ks + tid * 8) = *(const short8*)(kb + (bh * HW_ + kv0) * DK_ + tid * 8);
        // stage V^T tile [32][64] swizzled
        {
            short8 v = *(const short8*)(vt + (bh * DK_ + vrow) * HW_ + kv0 + vch * 8);
            *(short8*)((char*)Vs + vrow * 128 + ((vch * 16) ^ ((vrow & 7) << 4))) = v;
        }
        __syncthreads();

        // S^T = K · Qs^T + bias (bias preloaded as MFMA C operand)
        short8 qf = *(const short8*)(Qs + (w * 16 + c16) * DK_ + g * 8);
        f32x4 st[4];
        #pragma unroll
        for (int mt = 0; mt < 4; mt++) {
            float4 bi = *(const float4*)(Brow + kv0 + mt * 16 + g * 4);
            f32x4 acc; acc[0] = bi.x; acc[1] = bi.y; acc[2] = bi.z; acc[3] = bi.w;
            short8 kf = *(const short8*)(Ks + (mt * 16 + c16) * DK_ + g * 8);
            st[mt] = __builtin_amdgcn_mfma_f32_16x16x32_bf16(kf, qf, acc, 0, 0, 0);
        }

        // online softmax over this tile's 64 keys (column q = c16)
        float mx = m_run;
        #pragma unroll
        for (int mt = 0; mt < 4; mt++)
            #pragma unroll
            for (int rg = 0; rg < 4; rg++) mx = fmaxf(mx, st[mt][rg]);
        mx = fmaxf(mx, __shfl_xor(mx, 16));
        mx = fmaxf(mx, __shfl_xor(mx, 32));
        float f = __expf(m_run - mx);
        m_run = mx;
        float s = 0.f;
        #pragma unroll
        for (int mt = 0; mt < 4; mt++)
            #pragma unroll
            for (int rg = 0; rg < 4; rg++) {
                float e_ = __expf(st[mt][rg] - mx);
                st[mt][rg] = e_;
                s += e_;
            }
        s += __shfl_xor(s, 16);
        s += __shfl_xor(s, 32);
        l_run = l_run * f + s;

        // rescale O rows (row q' = g*4+reg needs f(q'): pull from lane q')
        int fv = __float_as_int(f);
        #pragma unroll
        for (int rg = 0; rg < 4; rg++) {
            float fr = __int_as_float(__builtin_amdgcn_ds_bpermute((g * 4 + rg) << 2, fv));
            ot[0][rg] *= fr;
            ot[1][rg] *= fr;
        }

        // P -> per-wave LDS (bf16, swizzled), then PV MFMA
        #pragma unroll
        for (int mt = 0; mt < 4; mt++) {
            unsigned lo = pack_bf16(st[mt][0], st[mt][1]);
            unsigned hi = pack_bf16(st[mt][2], st[mt][3]);
            uint32x2 pr; pr[0] = lo; pr[1] = hi;
            *(uint32x2*)(pbase + c16 * 128 + ((mt * 32 + g * 8) ^ ((c16 & 7) << 4))) = pr;
        }
        #pragma unroll
        for (int kt = 0; kt < 2; kt++) {
            short8 pf = *(const short8*)(pbase + c16 * 128 + ((kt * 64 + g * 16) ^ ((c16 & 7) << 4)));
            #pragma unroll
            for (int nt = 0; nt < 2; nt++) {
                short8 vf = *(const short8*)((char*)Vs + (c16 + 16 * nt) * 128 + ((kt * 64 + g * 16) ^ ((c16 & 7) << 4)));
                ot[nt] = __builtin_amdgcn_mfma_f32_16x16x32_bf16(pf, vf, ot[nt], 0, 0, 0);
            }
        }
    }

    // epilogue: divide by row sum, write ao[b][q][h*32+dv]
    float linv = 1.f / l_run;
    int lrv = __float_as_int(linv);
    #pragma unroll
    for (int rg = 0; rg < 4; rg++) {
        float li = __int_as_float(__builtin_amdgcn_ds_bpermute((g * 4 + rg) << 2, lrv));
        int qg = qt * 64 + w * 16 + g * 4 + rg;
        #pragma unroll
        for (int nt = 0; nt < 2; nt++)
            ao[(b * HW_ + qg) * C_ + h * DK_ + nt * 16 + c16] = ot[nt][rg] * li;
    }
}

// ---------------- stage 5: output projection + raw-reshape residual ----------
__global__ void k_out(const float* __restrict__ ao, const float* __restrict__ Wo,
                      const float* __restrict__ bo, const float* __restrict__ x,
                      float* __restrict__ out) {
    __shared__ float as_[C_][4];
    int b = blockIdx.x >> 8, i0 = (blockIdx.x & 255) << 2;
    int e = threadIdx.x;
    for (int ii = 0; ii < 4; ii++)
        as_[e][ii] = ao[(b * HW_ + i0 + ii) * C_ + e];
    __syncthreads();
    float acc[4];
    float boe = bo[e];
    #pragma unroll
    for (int ii = 0; ii < 4; ii++) acc[ii] = boe;
    for (int c = 0; c < C_; c++) {
        float w = Wo[c * 256 + e];
        #pragma unroll
        for (int ii = 0; ii < 4; ii++) acc[ii] += as_[c][ii] * w;
    }
    for (int ii = 0; ii < 4; ii++) {
        int idx = b * (C_ * HW_) + (i0 + ii) * 256 + e;
        out[idx] = acc[ii] + x[idx];
    }
}

extern "C" void kernel_launch(void* const* d_in, const int* in_sizes, int n_in,
                              void* d_out, int out_size, void* d_ws, size_t ws_size,
                              hipStream_t stream) {
    const float* x   = (const float*)d_in[0];
    const float* Wq  = (const float*)d_in[1];
    const float* bq  = (const float*)d_in[2];
    const float* ckw = (const float*)d_in[3];
    const float* ckb = (const float*)d_in[4];
    const float* Wk  = (const float*)d_in[5];
    const float* bk  = (const float*)d_in[6];
    const float* cvw = (const float*)d_in[7];
    const float* cvb = (const float*)d_in[8];
    const float* Wv  = (const float*)d_in[9];
    const float* bv  = (const float*)d_in[10];
    const float* Wo  = (const float*)d_in[11];
    const float* bo  = (const float*)d_in[12];
    const float* Bb  = (const float*)d_in[13];
    float* ws  = (float*)d_ws;
    float* out = (float*)d_out;

    short* xb = (short*)(ws + F_XB);
    short* wt = (short*)(ws + F_WT);
    short* qb = (short*)(ws + F_QB);
    short* kb = (short*)(ws + F_KB);
    short* vt = (short*)(ws + F_VT);

    k_part    <<<2048, 256, 0, stream>>>(x, ws + F_PART);
    k_stats   <<<1,    256, 0, stream>>>(ws + F_PART, ws + F_STATS);
    k_prep_x  <<<128,  256, 0, stream>>>(x, xb);
    k_prep_w  <<<1152, 256, 0, stream>>>(ckw, cvw, wt);
    k_conv_mfma<<<512, 256, 0, stream>>>(xb, wt, ckb, cvb, ws + F_YK2, ws + F_YV2);
    k_proj    <<<2048, 256, 0, stream>>>(x, ws + F_YK2, ws + F_YV2,
                                         Wq, bq, Wk, bk, Wv, bv,
                                         ws + F_STATS, qb, kb, vt);
    k_attn    <<<1024, 256, 0, stream>>>(qb, kb, vt, Bb, ws + F_AO);
    k_out     <<<2048, 256, 0, stream>>>(ws + F_AO, Wo, bo, x, out);
}

// Round 6
// 183.426 us; speedup vs baseline: 9.5870x; 1.3147x over previous
//
#include <hip/hip_runtime.h>
#include <hip/hip_bf16.h>
#include <math.h>

#define B_     8
#define C_     256
#define HW_    1024
#define NTOT   (B_*C_*HW_)     // 2097152
#define HEADS_ 8
#define DK_    32
#define SCALE_ 0.17677669529663687f  // 32^-0.5

// workspace layout (float offsets) — identical footprint to R5
#define F_STATS 0
#define F_PART  16
#define F_YK2   8192
#define F_YV2   (F_YK2 + NTOT)
#define F_XB    (F_YV2 + NTOT)            // NTOT shorts
#define F_WT    (F_XB + NTOT/2)           // conv w: 1179648 shorts; later wqt_all (262144 shorts) + beta0
#define F_QB    (F_WT + 589824)
#define F_KB    (F_QB + NTOT/2)
#define F_VT    (F_KB + NTOT/2)
// aliases: aob (bf16 attn out) over yk2; wqt_all+beta0 over conv wt (after conv)

typedef float f32x4 __attribute__((ext_vector_type(4)));
typedef short short8 __attribute__((ext_vector_type(8)));

__device__ __forceinline__ short bf16s(float f) {
    __hip_bfloat16 h = __float2bfloat16(f);
    return *(short*)&h;
}
__device__ __forceinline__ unsigned pack_bf16(float a, float b) {
    unsigned ua = (unsigned short)bf16s(a);
    unsigned ub = (unsigned short)bf16s(b);
    return ua | (ub << 16);
}

// ---------------- stage 1: global mean/var ----------------
__global__ void k_part(const float* __restrict__ x, float* __restrict__ part) {
    __shared__ float ls[4], ls2[4];
    float s = 0.f, s2 = 0.f;
    for (int i = blockIdx.x * 256 + threadIdx.x; i < NTOT; i += 2048 * 256) {
        float v = x[i]; s += v; s2 += v * v;
    }
    for (int o = 32; o; o >>= 1) { s += __shfl_down(s, o); s2 += __shfl_down(s2, o); }
    int wid = threadIdx.x >> 6, lane = threadIdx.x & 63;
    if (lane == 0) { ls[wid] = s; ls2[wid] = s2; }
    __syncthreads();
    if (threadIdx.x == 0) {
        float a = 0.f, b = 0.f;
        for (int i = 0; i < 4; i++) { a += ls[i]; b += ls2[i]; }
        part[blockIdx.x * 2] = a; part[blockIdx.x * 2 + 1] = b;
    }
}

__global__ void k_stats(const float* __restrict__ part, float* __restrict__ stats) {
    __shared__ float ls[256], ls2[256];
    float s = 0.f, s2 = 0.f;
    for (int i = threadIdx.x; i < 2048; i += 256) { s += part[2 * i]; s2 += part[2 * i + 1]; }
    ls[threadIdx.x] = s; ls2[threadIdx.x] = s2;
    __syncthreads();
    for (int off = 128; off; off >>= 1) {
        if (threadIdx.x < off) { ls[threadIdx.x] += ls[threadIdx.x + off]; ls2[threadIdx.x] += ls2[threadIdx.x + off]; }
        __syncthreads();
    }
    if (threadIdx.x == 0) {
        float m = ls[0] / (float)NTOT;
        float var = ls2[0] / (float)NTOT - m * m;
        stats[0] = m;
        stats[1] = rsqrtf(var + 1e-5f);
    }
}

// ---------------- prep: x -> xb[b][p][ci] bf16 ----------------
__global__ void k_prep_x(const float* __restrict__ x, short* __restrict__ xb) {
    __shared__ short t[64 * 258];
    int b = blockIdx.x >> 4, p0 = (blockIdx.x & 15) << 6;
    int tid = threadIdx.x;
    for (int i = tid; i < 256 * 64; i += 256) {
        int ci = i >> 6, p = i & 63;
        t[p * 258 + ci] = bf16s(x[(b * C_ + ci) * HW_ + p0 + p]);
    }
    __syncthreads();
    for (int i = tid; i < 64 * 256; i += 256) {
        int p = i >> 8, ci = i & 255;
        xb[(b * HW_ + p0 + p) * C_ + ci] = t[p * 258 + ci];
    }
}

// ---------------- prep: conv weights -> wt[tap][n(512)][ci] bf16 ------------
__global__ void k_prep_w(const float* __restrict__ wk, const float* __restrict__ wv,
                         short* __restrict__ wt) {
    int idx = blockIdx.x * 256 + threadIdx.x;
    int ci0 = (idx << 2) & 255;
    int rest = idx >> 6;
    int n = rest & 511, tap = rest >> 9;
    const float* src = (n < 256) ? (wk + (n * C_) * 9) : (wv + ((n - 256) * C_) * 9);
    short4 o;
    short* op = (short*)&o;
    for (int u = 0; u < 4; u++)
        op[u] = bf16s(src[(ci0 + u) * 9 + tap]);
    *(short4*)&wt[((tap * 512 + n) * C_) + ci0] = o;
}

// ---------------- prep: proj weights -> wt4[m][e][c] bf16 (transposed) ------
// grid 64 = 4 mats x 16 (4x4 tiles of 64x64); block 256
__global__ void k_prep_pw(const float* __restrict__ Wq, const float* __restrict__ Wk,
                          const float* __restrict__ Wv, const float* __restrict__ Wo,
                          short* __restrict__ wt4) {
    __shared__ short t[64 * 66];
    int mi = blockIdx.x >> 4, tl = blockIdx.x & 15;
    int c0 = (tl >> 2) * 64, e0 = (tl & 3) * 64;
    const float* W = mi == 0 ? Wq : mi == 1 ? Wk : mi == 2 ? Wv : Wo;
    int tid = threadIdx.x;
    for (int i = tid; i < 4096; i += 256) {
        int cl = i >> 6, el = i & 63;
        t[cl * 66 + el] = bf16s(W[(c0 + cl) * 256 + e0 + el]);
    }
    __syncthreads();
    for (int i = tid; i < 4096; i += 256) {
        int el = i >> 6, cl = i & 63;
        wt4[mi * 65536 + (e0 + el) * 256 + c0 + cl] = t[cl * 66 + el];
    }
}

// ---------------- prep: beta0[e] = (bq[e] - m*r*colsum(Wq[:,e])) * SCALE ----
__global__ void k_prep_beta(const float* __restrict__ Wq, const float* __restrict__ bq,
                            const float* __restrict__ stats, float* __restrict__ beta0) {
    __shared__ float ps[1024];
    int t = threadIdx.x, e = t & 255, part = t >> 8;
    float s = 0.f;
    for (int c = part * 64; c < part * 64 + 64; c++) s += Wq[c * 256 + e];
    ps[t] = s;
    __syncthreads();
    if (t < 256) {
        float cs = ps[t] + ps[t + 256] + ps[t + 512] + ps[t + 768];
        beta0[t] = (bq[t] - stats[0] * stats[1] * cs) * SCALE_;
    }
}

// ---------------- conv via MFMA implicit GEMM (both convs, N=512) -----------
__device__ __forceinline__ int a_off(int slot, int chunk) {
    int c = chunk ^ (slot & 3);
    int s = slot ^ ((slot >> 2) & 1);
    return s * 64 + c * 16;
}

__global__ void k_conv_mfma(const short* __restrict__ xb, const short* __restrict__ wt,
                            const float* __restrict__ bk, const float* __restrict__ bv,
                            float* __restrict__ yk2, float* __restrict__ yv2) {
    __shared__ short a_lds[136 * 32];
    int bid = blockIdx.x;
    int b = bid >> 6, pt = (bid >> 2) & 15, nt = bid & 3;
    int R0 = pt * 2;
    int tid = threadIdx.x;
    int w = tid >> 6, l = tid & 63;
    int wm = w >> 1, wn = w & 1;
    int col16 = l & 15, kq = l >> 4;

    f32x4 acc[2][4];
    #pragma unroll
    for (int m = 0; m < 2; m++)
        #pragma unroll
        for (int n = 0; n < 4; n++) acc[m][n] = (f32x4)0.f;

    const short* wbase = wt + (nt * 128 + wn * 64 + col16) * C_ + kq * 8;

    for (int ci0 = 0; ci0 < C_; ci0 += 32) {
        if (ci0) __syncthreads();
        for (int i = tid; i < 544; i += 256) {
            int slot = i >> 2, chunk = i & 3;
            int ty = slot / 34, tx = slot - ty * 34;
            int Y = R0 - 1 + ty, X = tx - 1;
            short8 v = (short8)0;
            if ((unsigned)Y < 32u && (unsigned)X < 32u)
                v = *(const short8*)(xb + ((b * HW_ + Y * 32 + X) * C_ + ci0 + chunk * 8));
            *(short8*)((char*)a_lds + a_off(slot, chunk)) = v;
        }
        __syncthreads();

        #pragma unroll
        for (int tap = 0; tap < 9; tap++) {
            const int dyi = tap / 3, dxi = tap % 3;
            short8 bf[4];
            #pragma unroll
            for (int nf = 0; nf < 4; nf++)
                bf[nf] = *(const short8*)(wbase + (tap * 512 + nf * 16) * C_ + ci0);
            short8 af[2];
            #pragma unroll
            for (int mf = 0; mf < 2; mf++) {
                int r = wm * 32 + mf * 16 + col16;
                int slot = ((r >> 5) + dyi) * 34 + (r & 31) + dxi;
                af[mf] = *(const short8*)((char*)a_lds + a_off(slot, kq));
            }
            #pragma unroll
            for (int mf = 0; mf < 2; mf++)
                #pragma unroll
                for (int nf = 0; nf < 4; nf++)
                    acc[mf][nf] = __builtin_amdgcn_mfma_f32_16x16x32_bf16(af[mf], bf[nf], acc[mf][nf], 0, 0, 0);
        }
    }

    const bool isv = (nt >= 2);
    float* dst = isv ? yv2 : yk2;
    const float* bias = isv ? bv : bk;
    int cbase = ((nt & 1) * 128) + wn * 64 + col16;
    #pragma unroll
    for (int nf = 0; nf < 4; nf++) {
        int co = cbase + nf * 16;
        float bi = bias[co];
        #pragma unroll
        for (int mf = 0; mf < 2; mf++) {
            #pragma unroll
            for (int r = 0; r < 4; r++) {
                int pixel = pt * 64 + wm * 32 + mf * 16 + kq * 4 + r;
                dst[(b * HW_ + pixel) * C_ + co] = acc[mf][nf][r] + bi;
            }
        }
    }
}

// ---------------- stage 3: projections via MFMA -----------------------------
// grid (3, 32, 8) = proj x ptile(32px) x b; block 256 = 4 waves (wave: 32px x 64e)
__global__ void k_proj_mfma(const short* __restrict__ xb,
                            const float* __restrict__ yk2, const float* __restrict__ yv2,
                            const short* __restrict__ wt4,
                            const float* __restrict__ bkp, const float* __restrict__ bvp,
                            const float* __restrict__ stats, const float* __restrict__ beta0,
                            short* __restrict__ qb, short* __restrict__ kb,
                            short* __restrict__ vt) {
    __shared__ char smem[17408];   // A-tile 16384 | repack 4 x 2176 shorts
    int pj = blockIdx.x, pt = blockIdx.y, b = blockIdx.z;
    int p0 = pt * 32;
    int tid = threadIdx.x, w = tid >> 6, l = tid & 63;
    int c16 = l & 15, kq = l >> 4;

    // stage A tile: 8 slabs x [32 px][32 ci], conv-style swizzle
    if (pj == 0) {
        #pragma unroll
        for (int it = 0; it < 4; it++) {
            int i = it * 256 + tid;
            int slab = i >> 7, rem = i & 127, slot = rem >> 2, chunk = rem & 3;
            short8 v = *(const short8*)(xb + ((b * HW_ + p0 + slot) * C_ + slab * 32 + chunk * 8));
            *(short8*)(smem + slab * 2048 + a_off(slot, chunk)) = v;
        }
    } else {
        const float* src = (pj == 1) ? yk2 : yv2;
        #pragma unroll
        for (int it = 0; it < 4; it++) {
            int i = it * 256 + tid;
            int slab = i >> 7, rem = i & 127, slot = rem >> 2, chunk = rem & 3;
            const float* sp = src + (b * HW_ + p0 + slot) * C_ + slab * 32 + chunk * 8;
            float4 f0 = *(const float4*)sp;
            float4 f1 = *(const float4*)(sp + 4);
            short8 v;
            v[0] = bf16s(f0.x); v[1] = bf16s(f0.y); v[2] = bf16s(f0.z); v[3] = bf16s(f0.w);
            v[4] = bf16s(f1.x); v[5] = bf16s(f1.y); v[6] = bf16s(f1.z); v[7] = bf16s(f1.w);
            *(short8*)(smem + slab * 2048 + a_off(slot, chunk)) = v;
        }
    }
    __syncthreads();

    const short* wt_p = wt4 + pj * 65536;
    f32x4 acc[2][4];
    #pragma unroll
    for (int m = 0; m < 2; m++)
        #pragma unroll
        for (int n = 0; n < 4; n++) acc[m][n] = (f32x4)0.f;

    for (int s = 0; s < 8; s++) {
        short8 af[2], bf[4];
        #pragma unroll
        for (int mf = 0; mf < 2; mf++)
            af[mf] = *(const short8*)(smem + s * 2048 + a_off(mf * 16 + c16, kq));
        #pragma unroll
        for (int nf = 0; nf < 4; nf++)
            bf[nf] = *(const short8*)(wt_p + (w * 64 + nf * 16 + c16) * 256 + s * 32 + kq * 8);
        #pragma unroll
        for (int mf = 0; mf < 2; mf++)
            #pragma unroll
            for (int nf = 0; nf < 4; nf++)
                acc[mf][nf] = __builtin_amdgcn_mfma_f32_16x16x32_bf16(af[mf], bf[nf], acc[mf][nf], 0, 0, 0);
    }

    float alpha = (pj == 0) ? stats[1] * SCALE_ : 1.f;
    float beta[4];
    #pragma unroll
    for (int nf = 0; nf < 4; nf++) {
        int e = w * 64 + nf * 16 + c16;
        beta[nf] = (pj == 0) ? beta0[e] : (pj == 1 ? bkp[e] : bvp[e]);
    }
    __syncthreads();   // A-tile dead; reuse smem for repack

    short* rp = (short*)smem + w * 2176;
    if (pj < 2) {
        // repack [px 32][66] -> coalesced [bh][p][d] stores
        #pragma unroll
        for (int mf = 0; mf < 2; mf++)
            #pragma unroll
            for (int nf = 0; nf < 4; nf++)
                #pragma unroll
                for (int rg = 0; rg < 4; rg++) {
                    int px = mf * 16 + kq * 4 + rg, el = nf * 16 + c16;
                    rp[px * 66 + el] = bf16s(alpha * acc[mf][nf][rg] + beta[nf]);
                }
        __syncthreads();
        short* dst = (pj == 0) ? qb : kb;
        #pragma unroll
        for (int j = 0; j < 4; j++) {
            int px = j * 8 + (l >> 3), el = (l & 7) * 8;
            short8 v = *(const short8*)(rp + px * 66 + el);
            int e = w * 64 + el, h = e >> 5, d = e & 31;
            *(short8*)(dst + ((b * 8 + h) * HW_ + p0 + px) * DK_ + d) = v;
        }
    } else {
        // repack [el 64][34] -> coalesced vt[bh][d][p] stores
        #pragma unroll
        for (int mf = 0; mf < 2; mf++)
            #pragma unroll
            for (int nf = 0; nf < 4; nf++)
                #pragma unroll
                for (int rg = 0; rg < 4; rg++) {
                    int px = mf * 16 + kq * 4 + rg, el = nf * 16 + c16;
                    rp[el * 34 + px] = bf16s(acc[mf][nf][rg] + beta[nf]);
                }
        __syncthreads();
        #pragma unroll
        for (int j = 0; j < 4; j++) {
            int el = j * 16 + (l >> 2), px = (l & 3) * 8;
            short8 v = *(const short8*)(rp + el * 34 + px);
            int e = w * 64 + el, h = e >> 5, d = e & 31;
            *(short8*)(vt + ((b * 8 + h) * DK_ + d) * HW_ + p0 + px) = v;
        }
    }
}

// ---------------- stage 4: attention (MFMA flash, swapped QK^T) -------------
__global__ void k_attn(const short* __restrict__ qb, const short* __restrict__ kb,
                       const short* __restrict__ vt, const float* __restrict__ Bb,
                       short* __restrict__ ao) {
    __shared__ __align__(16) short Qs[64 * 32];
    __shared__ __align__(16) short Ks[64 * 32];
    __shared__ __align__(16) short Vs[32 * 64];
    __shared__ __align__(16) short Ps[4][16 * 64];
    int bid = blockIdx.x;
    int h = bid & 7, b = (bid >> 3) & 7, qt = bid >> 6;
    int bh = b * HEADS_ + h;
    int tid = threadIdx.x, w = tid >> 6, l = tid & 63;
    int g = l >> 4, c16 = l & 15;

    *(short8*)(Qs + tid * 8) = *(const short8*)(qb + (bh * HW_ + qt * 64) * DK_ + tid * 8);

    const float* Brow = Bb + (h * HW_ + qt * 64 + w * 16 + c16) * HW_;
    float m_run = -1e30f, l_run = 0.f;
    f32x4 ot[2];
    ot[0] = (f32x4)0.f; ot[1] = (f32x4)0.f;
    char* pbase = (char*)&Ps[w][0];
    int vrow = tid >> 3, vch = tid & 7;

    for (int kv0 = 0; kv0 < HW_; kv0 += 64) {
        __syncthreads();
        *(short8*)(Ks + tid * 8) = *(const short8*)(kb + (bh * HW_ + kv0) * DK_ + tid * 8);
        {
            short8 v = *(const short8*)(vt + (bh * DK_ + vrow) * HW_ + kv0 + vch * 8);
            *(short8*)((char*)Vs + vrow * 128 + ((vch * 16) ^ ((vrow & 7) << 4))) = v;
        }
        __syncthreads();

        short8 qf = *(const short8*)(Qs + (w * 16 + c16) * DK_ + g * 8);
        f32x4 st[4];
        #pragma unroll
        for (int mt = 0; mt < 4; mt++) {
            float4 bi = *(const float4*)(Brow + kv0 + mt * 16 + g * 4);
            f32x4 acc; acc[0] = bi.x; acc[1] = bi.y; acc[2] = bi.z; acc[3] = bi.w;
            short8 kf = *(const short8*)(Ks + (mt * 16 + c16) * DK_ + g * 8);
            st[mt] = __builtin_amdgcn_mfma_f32_16x16x32_bf16(kf, qf, acc, 0, 0, 0);
        }

        float mx = m_run;
        #pragma unroll
        for (int mt = 0; mt < 4; mt++)
            #pragma unroll
            for (int rg = 0; rg < 4; rg++) mx = fmaxf(mx, st[mt][rg]);
        mx = fmaxf(mx, __shfl_xor(mx, 16));
        mx = fmaxf(mx, __shfl_xor(mx, 32));
        float f = __expf(m_run - mx);
        m_run = mx;
        float s = 0.f;
        #pragma unroll
        for (int mt = 0; mt < 4; mt++)
            #pragma unroll
            for (int rg = 0; rg < 4; rg++) {
                float e_ = __expf(st[mt][rg] - mx);
                st[mt][rg] = e_;
                s += e_;
            }
        s += __shfl_xor(s, 16);
        s += __shfl_xor(s, 32);
        l_run = l_run * f + s;

        int fv = __float_as_int(f);
        #pragma unroll
        for (int rg = 0; rg < 4; rg++) {
            float fr = __int_as_float(__builtin_amdgcn_ds_bpermute((g * 4 + rg) << 2, fv));
            ot[0][rg] *= fr;
            ot[1][rg] *= fr;
        }

        #pragma unroll
        for (int mt = 0; mt < 4; mt++) {
            unsigned lo = pack_bf16(st[mt][0], st[mt][1]);
            unsigned hi = pack_bf16(st[mt][2], st[mt][3]);
            unsigned long long pr = (unsigned long long)lo | ((unsigned long long)hi << 32);
            *(unsigned long long*)(pbase + c16 * 128 + ((mt * 32 + g * 8) ^ ((c16 & 7) << 4))) = pr;
        }
        #pragma unroll
        for (int kt = 0; kt < 2; kt++) {
            short8 pf = *(const short8*)(pbase + c16 * 128 + ((kt * 64 + g * 16) ^ ((c16 & 7) << 4)));
            #pragma unroll
            for (int nt = 0; nt < 2; nt++) {
                short8 vf = *(const short8*)((char*)Vs + (c16 + 16 * nt) * 128 + ((kt * 64 + g * 16) ^ ((c16 & 7) << 4)));
                ot[nt] = __builtin_amdgcn_mfma_f32_16x16x32_bf16(pf, vf, ot[nt], 0, 0, 0);
            }
        }
    }

    float linv = 1.f / l_run;
    int lrv = __float_as_int(linv);
    #pragma unroll
    for (int rg = 0; rg < 4; rg++) {
        float li = __int_as_float(__builtin_amdgcn_ds_bpermute((g * 4 + rg) << 2, lrv));
        int qg = qt * 64 + w * 16 + g * 4 + rg;
        #pragma unroll
        for (int nt = 0; nt < 2; nt++)
            ao[(b * HW_ + qg) * C_ + h * DK_ + nt * 16 + c16] = bf16s(ot[nt][rg] * li);
    }
}

// ---------------- stage 5: output projection via MFMA + residual ------------
// grid (32, 8) = ptile(32px) x b; block 256 = 4 waves (wave: 32px x 64e)
__global__ void k_out_mfma(const short* __restrict__ aob, const short* __restrict__ wot,
                           const float* __restrict__ bo, const float* __restrict__ x,
                           float* __restrict__ out) {
    __shared__ char smem[16384];
    int pt = blockIdx.x, b = blockIdx.y;
    int p0 = pt * 32;
    int tid = threadIdx.x, w = tid >> 6, l = tid & 63;
    int c16 = l & 15, kq = l >> 4;

    #pragma unroll
    for (int it = 0; it < 4; it++) {
        int i = it * 256 + tid;
        int slab = i >> 7, rem = i & 127, slot = rem >> 2, chunk = rem & 3;
        short8 v = *(const short8*)(aob + ((b * HW_ + p0 + slot) * C_ + slab * 32 + chunk * 8));
        *(short8*)(smem + slab * 2048 + a_off(slot, chunk)) = v;
    }
    __syncthreads();

    f32x4 acc[2][4];
    #pragma unroll
    for (int m = 0; m < 2; m++)
        #pragma unroll
        for (int n = 0; n < 4; n++) acc[m][n] = (f32x4)0.f;

    for (int s = 0; s < 8; s++) {
        short8 af[2], bf[4];
        #pragma unroll
        for (int mf = 0; mf < 2; mf++)
            af[mf] = *(const short8*)(smem + s * 2048 + a_off(mf * 16 + c16, kq));
        #pragma unroll
        for (int nf = 0; nf < 4; nf++)
            bf[nf] = *(const short8*)(wot + (w * 64 + nf * 16 + c16) * 256 + s * 32 + kq * 8);
        #pragma unroll
        for (int mf = 0; mf < 2; mf++)
            #pragma unroll
            for (int nf = 0; nf < 4; nf++)
                acc[mf][nf] = __builtin_amdgcn_mfma_f32_16x16x32_bf16(af[mf], bf[nf], acc[mf][nf], 0, 0, 0);
    }

    #pragma unroll
    for (int nf = 0; nf < 4; nf++) {
        int e = w * 64 + nf * 16 + c16;
        float bov = bo[e];
        #pragma unroll
        for (int mf = 0; mf < 2; mf++) {
            #pragma unroll
            for (int rg = 0; rg < 4; rg++) {
                int px = mf * 16 + kq * 4 + rg;
                int idx = b * (C_ * HW_) + (p0 + px) * 256 + e;  // raw reshape residual
                out[idx] = acc[mf][nf][rg] + bov + x[idx];
            }
        }
    }
}

extern "C" void kernel_launch(void* const* d_in, const int* in_sizes, int n_in,
                              void* d_out, int out_size, void* d_ws, size_t ws_size,
                              hipStream_t stream) {
    const float* x   = (const float*)d_in[0];
    const float* Wq  = (const float*)d_in[1];
    const float* bq  = (const float*)d_in[2];
    const float* ckw = (const float*)d_in[3];
    const float* ckb = (const float*)d_in[4];
    const float* Wk  = (const float*)d_in[5];
    const float* bk  = (const float*)d_in[6];
    const float* cvw = (const float*)d_in[7];
    const float* cvb = (const float*)d_in[8];
    const float* Wv  = (const float*)d_in[9];
    const float* bv  = (const float*)d_in[10];
    const float* Wo  = (const float*)d_in[11];
    const float* bo  = (const float*)d_in[12];
    const float* Bb  = (const float*)d_in[13];
    float* ws  = (float*)d_ws;
    float* out = (float*)d_out;

    short* xb      = (short*)(ws + F_XB);
    short* wt      = (short*)(ws + F_WT);          // conv weights (bf16)
    short* wt4     = (short*)(ws + F_WT);          // proj weights, overwrite after conv
    float* beta0   = ws + F_WT + 131072;
    short* qb      = (short*)(ws + F_QB);
    short* kb      = (short*)(ws + F_KB);
    short* vt      = (short*)(ws + F_VT);
    short* aob     = (short*)(ws + F_YK2);         // alias over yk2 (dead after proj)
    short* wot     = wt4 + 3 * 65536;

    k_part     <<<2048, 256, 0, stream>>>(x, ws + F_PART);
    k_stats    <<<1,    256, 0, stream>>>(ws + F_PART, ws + F_STATS);
    k_prep_x   <<<128,  256, 0, stream>>>(x, xb);
    k_prep_w   <<<1152, 256, 0, stream>>>(ckw, cvw, wt);
    k_conv_mfma<<<512,  256, 0, stream>>>(xb, wt, ckb, cvb, ws + F_YK2, ws + F_YV2);
    k_prep_pw  <<<64,   256, 0, stream>>>(Wq, Wk, Wv, Wo, wt4);
    k_prep_beta<<<1,   1024, 0, stream>>>(Wq, bq, ws + F_STATS, beta0);
    k_proj_mfma<<<dim3(3, 32, 8), 256, 0, stream>>>(xb, ws + F_YK2, ws + F_YV2,
                                                    wt4, bk, bv, ws + F_STATS, beta0,
                                                    qb, kb, vt);
    k_attn     <<<1024, 256, 0, stream>>>(qb, kb, vt, Bb, aob);
    k_out_mfma <<<dim3(32, 8), 256, 0, stream>>>(aob, wot, bo, x, out);
}